// Round 12
// baseline (525.406 us; speedup 1.0000x reference)
//
#include <hip/hip_runtime.h>
#include <math.h>

#define NUM_EMB 512
#define EDIM 64
#define BATCH 32
#define HW 4096
#define NROWS (BATCH * HW)        // 131072
#define NQ (NROWS * EDIM)         // 8388608

#define RPB 64                    // rows per block (lane = row)

// LDS layout in floats (5696 floats = 22784 B)
#define XOFF 0                    // x[c][r] : c*64 + r  (64 x 64)
#define T2OFF 4096                // t2[512]
#define CBOFF 4608                // combine best [w][64]
#define CKOFF 5120                // combine bestk [w][64] (int)
#define KFOFF 5632                // final K per row [64] (int)
#define SFLOATS 5696

// numpy pairwise_sum for n=64 contiguous fp32 (tiny prep kernel only).
__device__ __forceinline__ float pairwise8_64(const float* v) {
    float r0 = v[0], r1 = v[1], r2 = v[2], r3 = v[3];
    float r4 = v[4], r5 = v[5], r6 = v[6], r7 = v[7];
#pragma unroll
    for (int i = 8; i < 64; i += 8) {
        r0 = __fadd_rn(r0, v[i + 0]);
        r1 = __fadd_rn(r1, v[i + 1]);
        r2 = __fadd_rn(r2, v[i + 2]);
        r3 = __fadd_rn(r3, v[i + 3]);
        r4 = __fadd_rn(r4, v[i + 4]);
        r5 = __fadd_rn(r5, v[i + 5]);
        r6 = __fadd_rn(r6, v[i + 6]);
        r7 = __fadd_rn(r7, v[i + 7]);
    }
    return __fadd_rn(__fadd_rn(__fadd_rn(r0, r1), __fadd_rn(r2, r3)),
                     __fadd_rn(__fadd_rn(r4, r5), __fadd_rn(r6, r7)));
}

// ws_f layout: [0] = loss sum accumulator, [8..8+511] = t2[k] = ||emb_k||^2
__global__ void vq_prep(const float* __restrict__ emb, float* __restrict__ ws_f) {
    int k = blockIdx.x * blockDim.x + threadIdx.x;
    if (k == 0) ws_f[0] = 0.0f;
    if (k < NUM_EMB) {
        const float* e = emb + k * EDIM;
        float sq[EDIM];
#pragma unroll
        for (int c = 0; c < EDIM; ++c) sq[c] = __fmul_rn(e[c], e[c]);
        ws_f[8 + k] = pairwise8_64(sq);
    }
}

// Round-11: move the e-operand OFF the LDS pipe (round 10's bottleneck:
// 6.3M ds_read_b128 ~ 123 us/CU-pipe). Wave w owns k in [64w,64w+64):
// e addresses are wave-uniform -> global_load_dwordx4 broadcast on the
// in-order vmcnt path (L1-resident 128KB table). x reads are ds_read_b32
// stride-1 (2 lanes/bank = free, m136). Per (row,k): one ascending-c FMA
// chain -> bit-exact vs numpy (verified absmax 0.0 rounds 1-10).
__global__ __launch_bounds__(512, 4) void vq_main(const float* __restrict__ z,
                                                  const float* __restrict__ emb,
                                                  float* __restrict__ out,
                                                  float* __restrict__ ws_f) {
    __shared__ float S[SFLOATS];
    const int tid  = threadIdx.x;
    const int lane = tid & 63;       // lane = local row
    const int w    = tid >> 6;       // wave id 0..7 -> k range
    const int bb   = blockIdx.x;
    const int b    = bb >> 6;        // 64 blocks per batch image
    const int hwb  = (bb & 63) << 6; // block's hw base (64 rows)

    const float* zb = z + (size_t)b * (EDIM * HW) + hwb;

    // ---- stage x[c][r] + t2 ----
    {
        const int r = tid & 63, cg = tid >> 6;   // 8 c's per thread
#pragma unroll
        for (int j = 0; j < 8; ++j) {
            const int c = cg * 8 + j;
            S[XOFF + c * 64 + r] = zb[(size_t)c * HW + r];  // coalesced lanes->r
        }
    }
    S[T2OFF + tid] = ws_f[8 + tid];
    __syncthreads();

    // ---- t1 for this lane's row: numpy pairwise-8, ascending c ----
    const float* xl = &S[XOFF + lane];   // stride 64 per c; 2 lanes/bank: free
    float p0 = __fmul_rn(xl[0 * 64], xl[0 * 64]);
    float p1 = __fmul_rn(xl[1 * 64], xl[1 * 64]);
    float p2 = __fmul_rn(xl[2 * 64], xl[2 * 64]);
    float p3 = __fmul_rn(xl[3 * 64], xl[3 * 64]);
    float p4 = __fmul_rn(xl[4 * 64], xl[4 * 64]);
    float p5 = __fmul_rn(xl[5 * 64], xl[5 * 64]);
    float p6 = __fmul_rn(xl[6 * 64], xl[6 * 64]);
    float p7 = __fmul_rn(xl[7 * 64], xl[7 * 64]);
#pragma unroll
    for (int m = 1; m < 8; ++m) {
        float v0 = xl[(8 * m + 0) * 64], v1 = xl[(8 * m + 1) * 64];
        float v2 = xl[(8 * m + 2) * 64], v3 = xl[(8 * m + 3) * 64];
        float v4 = xl[(8 * m + 4) * 64], v5 = xl[(8 * m + 5) * 64];
        float v6 = xl[(8 * m + 6) * 64], v7 = xl[(8 * m + 7) * 64];
        p0 = __fadd_rn(p0, __fmul_rn(v0, v0));
        p1 = __fadd_rn(p1, __fmul_rn(v1, v1));
        p2 = __fadd_rn(p2, __fmul_rn(v2, v2));
        p3 = __fadd_rn(p3, __fmul_rn(v3, v3));
        p4 = __fadd_rn(p4, __fmul_rn(v4, v4));
        p5 = __fadd_rn(p5, __fmul_rn(v5, v5));
        p6 = __fadd_rn(p6, __fmul_rn(v6, v6));
        p7 = __fadd_rn(p7, __fmul_rn(v7, v7));
    }
    const float t1 = __fadd_rn(__fadd_rn(__fadd_rn(p0, p1), __fadd_rn(p2, p3)),
                               __fadd_rn(__fadd_rn(p4, p5), __fadd_rn(p6, p7)));

    // ---- k loop: this wave's 64 k, 8 at a time ----
    const int k0 = w << 6;
    float best = INFINITY;
    int   bk   = k0;

    for (int kb = 0; kb < 8; ++kb) {
        const int kbase = k0 + kb * 8;
        // wave-uniform row pointers (vector loads, runtime-broadcast)
        const float4* e0r = (const float4*)(emb + (size_t)(kbase + 0) * EDIM);
        const float4* e1r = (const float4*)(emb + (size_t)(kbase + 1) * EDIM);
        const float4* e2r = (const float4*)(emb + (size_t)(kbase + 2) * EDIM);
        const float4* e3r = (const float4*)(emb + (size_t)(kbase + 3) * EDIM);
        const float4* e4r = (const float4*)(emb + (size_t)(kbase + 4) * EDIM);
        const float4* e5r = (const float4*)(emb + (size_t)(kbase + 5) * EDIM);
        const float4* e6r = (const float4*)(emb + (size_t)(kbase + 6) * EDIM);
        const float4* e7r = (const float4*)(emb + (size_t)(kbase + 7) * EDIM);

        float acc[8];
#pragma unroll
        for (int j = 0; j < 8; ++j) acc[j] = 0.0f;

#pragma unroll 2
        for (int cc = 0; cc < 16; ++cc) {       // 4 c's per iter
            const float4 e0 = e0r[cc], e1 = e1r[cc], e2 = e2r[cc], e3 = e3r[cc];
            const float4 e4 = e4r[cc], e5 = e5r[cc], e6 = e6r[cc], e7 = e7r[cc];
            const int cb4 = cc * 4;
            const float x0 = S[XOFF + (cb4 + 0) * 64 + lane];
            const float x1 = S[XOFF + (cb4 + 1) * 64 + lane];
            const float x2 = S[XOFF + (cb4 + 2) * 64 + lane];
            const float x3 = S[XOFF + (cb4 + 3) * 64 + lane];
            // each acc[j] visits c in ascending order (i outer)
            acc[0] = __fmaf_rn(x0, e0.x, acc[0]);
            acc[1] = __fmaf_rn(x0, e1.x, acc[1]);
            acc[2] = __fmaf_rn(x0, e2.x, acc[2]);
            acc[3] = __fmaf_rn(x0, e3.x, acc[3]);
            acc[4] = __fmaf_rn(x0, e4.x, acc[4]);
            acc[5] = __fmaf_rn(x0, e5.x, acc[5]);
            acc[6] = __fmaf_rn(x0, e6.x, acc[6]);
            acc[7] = __fmaf_rn(x0, e7.x, acc[7]);
            acc[0] = __fmaf_rn(x1, e0.y, acc[0]);
            acc[1] = __fmaf_rn(x1, e1.y, acc[1]);
            acc[2] = __fmaf_rn(x1, e2.y, acc[2]);
            acc[3] = __fmaf_rn(x1, e3.y, acc[3]);
            acc[4] = __fmaf_rn(x1, e4.y, acc[4]);
            acc[5] = __fmaf_rn(x1, e5.y, acc[5]);
            acc[6] = __fmaf_rn(x1, e6.y, acc[6]);
            acc[7] = __fmaf_rn(x1, e7.y, acc[7]);
            acc[0] = __fmaf_rn(x2, e0.z, acc[0]);
            acc[1] = __fmaf_rn(x2, e1.z, acc[1]);
            acc[2] = __fmaf_rn(x2, e2.z, acc[2]);
            acc[3] = __fmaf_rn(x2, e3.z, acc[3]);
            acc[4] = __fmaf_rn(x2, e4.z, acc[4]);
            acc[5] = __fmaf_rn(x2, e5.z, acc[5]);
            acc[6] = __fmaf_rn(x2, e6.z, acc[6]);
            acc[7] = __fmaf_rn(x2, e7.z, acc[7]);
            acc[0] = __fmaf_rn(x3, e0.w, acc[0]);
            acc[1] = __fmaf_rn(x3, e1.w, acc[1]);
            acc[2] = __fmaf_rn(x3, e2.w, acc[2]);
            acc[3] = __fmaf_rn(x3, e3.w, acc[3]);
            acc[4] = __fmaf_rn(x3, e4.w, acc[4]);
            acc[5] = __fmaf_rn(x3, e5.w, acc[5]);
            acc[6] = __fmaf_rn(x3, e6.w, acc[6]);
            acc[7] = __fmaf_rn(x3, e7.w, acc[7]);
        }

        // d = fl(fl(t1 + t2) - fl(2*p)); in-thread k ascending, strict <
#pragma unroll
        for (int j = 0; j < 8; ++j) {
            const float t2k = S[T2OFF + kbase + j];
            const float d = __fsub_rn(__fadd_rn(t1, t2k),
                                      __fmul_rn(2.0f, acc[j]));
            if (d < best) { best = d; bk = kbase + j; }
        }
    }

    // ---- combine across the 8 waves (contiguous ascending k ranges) ----
    S[CBOFF + w * 64 + lane] = best;
    ((int*)S)[CKOFF + w * 64 + lane] = bk;
    __syncthreads();

    if (tid < 64) {
        float B = INFINITY;
        int   K = 0;
        // lexicographic (d, k): exact numpy lowest-index tie-break
#pragma unroll
        for (int q = 0; q < 8; ++q) {
            const float bq = S[CBOFF + q * 64 + tid];
            const int   kq = ((int*)S)[CKOFF + q * 64 + tid];
            if (bq < B || (bq == B && kq < K)) { B = bq; K = kq; }
        }
        ((int*)S)[KFOFF + tid] = K;
        out[(size_t)NQ + 2 + bb * 64 + tid] = (float)K;   // idx as fp32
    }
    __syncthreads();

    // ---- epilogue: wave w writes c in [w*8, w*8+8) for all 64 rows ----
    {
        const int r = lane;
        const int K = ((int*)S)[KFOFF + r];
        const float* eb = emb + (size_t)K * EDIM;
        float s = 0.0f;
#pragma unroll
        for (int j = 0; j < 8; ++j) {
            const int c = w * 8 + j;
            const float x = S[XOFF + c * 64 + r];
            const float f = __fsub_rn(eb[c], x);     // divergent gather, L1/L2
            out[((size_t)b * EDIM + c) * HW + hwb + r] = __fadd_rn(x, f);
            s = __fmaf_rn(f, f, s);
        }
        // wave-level reduction of loss partial, one atomic per wave
#pragma unroll
        for (int off = 32; off > 0; off >>= 1) s += __shfl_down(s, off);
        if (lane == 0) atomicAdd(ws_f, s);
    }
}

__global__ void vq_final(const float* __restrict__ ws_f, float* __restrict__ out) {
    float m = ws_f[0] * (1.0f / (float)NQ);   // 2^-23, exact scaling
    out[NQ + 0] = m;
    out[NQ + 1] = m;
}

extern "C" void kernel_launch(void* const* d_in, const int* in_sizes, int n_in,
                              void* d_out, int out_size, void* d_ws, size_t ws_size,
                              hipStream_t stream) {
    const float* z = (const float*)d_in[0];     // [32, 64, 64, 64] fp32
    const float* emb = (const float*)d_in[1];   // [512, 64] fp32
    float* out = (float*)d_out;
    float* ws_f = (float*)d_ws;

    hipLaunchKernelGGL(vq_prep, dim3(1), dim3(512), 0, stream, emb, ws_f);
    hipLaunchKernelGGL(vq_main, dim3(NROWS / RPB), dim3(512), 0, stream, z, emb, out, ws_f);
    hipLaunchKernelGGL(vq_final, dim3(1), dim3(1), 0, stream, ws_f, out);
}

// Round 13
// 323.516 us; speedup vs baseline: 1.6241x; 1.6241x over previous
//
#include <hip/hip_runtime.h>
#include <math.h>

#define NUM_EMB 512
#define EDIM 64
#define BATCH 32
#define HW 4096
#define NROWS (BATCH * HW)        // 131072
#define NQ (NROWS * EDIM)         // 8388608

// LDS layout in floats (17152 floats = 68608 B -> 2 blocks/CU)
#define XOFF 0                    // x_t[c][r] : c*256 + r  (64 x 256)
#define T2OFF 16384               // t2[512]
#define T1OFF 16896               // t1[256]
#define CBOFF 0                   // combine best [kt][256]  (overlays x post-loop)
#define CKOFF 4096                // combine bestk [kt][256] (int, overlays x)
#define SFLOATS 17152

// numpy pairwise_sum for n=64 contiguous fp32 (tiny prep kernel only).
__device__ __forceinline__ float pairwise8_64(const float* v) {
    float r0 = v[0], r1 = v[1], r2 = v[2], r3 = v[3];
    float r4 = v[4], r5 = v[5], r6 = v[6], r7 = v[7];
#pragma unroll
    for (int i = 8; i < 64; i += 8) {
        r0 = __fadd_rn(r0, v[i + 0]);
        r1 = __fadd_rn(r1, v[i + 1]);
        r2 = __fadd_rn(r2, v[i + 2]);
        r3 = __fadd_rn(r3, v[i + 3]);
        r4 = __fadd_rn(r4, v[i + 4]);
        r5 = __fadd_rn(r5, v[i + 5]);
        r6 = __fadd_rn(r6, v[i + 6]);
        r7 = __fadd_rn(r7, v[i + 7]);
    }
    return __fadd_rn(__fadd_rn(__fadd_rn(r0, r1), __fadd_rn(r2, r3)),
                     __fadd_rn(__fadd_rn(r4, r5), __fadd_rn(r6, r7)));
}

// ws_f layout: [0] = loss sum accumulator, [8..8+511] = t2[k] = ||emb_k||^2
__global__ void vq_prep(const float* __restrict__ emb, float* __restrict__ ws_f) {
    int k = blockIdx.x * blockDim.x + threadIdx.x;
    if (k == 0) ws_f[0] = 0.0f;
    if (k < NUM_EMB) {
        const float* e = emb + k * EDIM;
        float sq[EDIM];
#pragma unroll
        for (int c = 0; c < EDIM; ++c) sq[c] = __fmul_rn(e[c], e[c]);
        ws_f[8 + k] = pairwise8_64(sq);
    }
}

// Round-13: acc[8][8] tile; x from LDS (conflict-free b128, the ONLY LDS user
// in the hot loop -> pipe at 0.75 of wall); e from global via ONE base pointer
// + compile-time offsets (offset:j*256+cc*16 <= 2032) -> zero per-load VALU,
// vmcnt-pipelined, L1/L2-hot (8KB sweep working set). No k-loop barriers.
// Per (row,k): ONE ascending-c FMA chain -> bit-exact (verified absmax 0.0).
__global__ __launch_bounds__(512, 4) void vq_main(const float* __restrict__ z,
                                                  const float* __restrict__ emb,
                                                  float* __restrict__ out,
                                                  float* __restrict__ ws_f) {
    __shared__ float S[SFLOATS];
    const int tid = threadIdx.x;
    const int rt  = tid & 31;       // row-thread
    const int kt  = tid >> 5;       // k-thread: 16, each owns k in [kt*32,kt*32+32)
    const int row0 = rt * 4;        // rows row0+i and 128+row0+i (conflict-free)
    const int bb  = blockIdx.x;
    const int b   = bb >> 4;        // batch (16 blocks per batch image)
    const int hwb = (bb & 15) << 8; // block's hw base (256 rows)

    const float* zb = z + (size_t)b * (EDIM * HW) + hwb;

    // ---- stage x_t[c][r] (transposed) + t2 ----
    {
        const int r = tid & 255, ch = tid >> 8;
#pragma unroll
        for (int j = 0; j < 32; ++j) {
            const int c = ch * 32 + j;
            S[XOFF + c * 256 + r] = zb[(size_t)c * HW + r];  // coalesced lanes->r
        }
    }
    S[T2OFF + tid] = ws_f[8 + tid];
    __syncthreads();

    // ---- t1 per row: numpy pairwise-8, ascending c, from x_t ----
    if (tid < 256) {
        const float* xr = &S[XOFF + tid];   // stride 256 per c
        float q0 = __fmul_rn(xr[0 * 256], xr[0 * 256]);
        float q1 = __fmul_rn(xr[1 * 256], xr[1 * 256]);
        float q2 = __fmul_rn(xr[2 * 256], xr[2 * 256]);
        float q3 = __fmul_rn(xr[3 * 256], xr[3 * 256]);
        float q4 = __fmul_rn(xr[4 * 256], xr[4 * 256]);
        float q5 = __fmul_rn(xr[5 * 256], xr[5 * 256]);
        float q6 = __fmul_rn(xr[6 * 256], xr[6 * 256]);
        float q7 = __fmul_rn(xr[7 * 256], xr[7 * 256]);
#pragma unroll
        for (int m = 1; m < 8; ++m) {
            float v0 = xr[(8 * m + 0) * 256], v1 = xr[(8 * m + 1) * 256];
            float v2 = xr[(8 * m + 2) * 256], v3 = xr[(8 * m + 3) * 256];
            float v4 = xr[(8 * m + 4) * 256], v5 = xr[(8 * m + 5) * 256];
            float v6 = xr[(8 * m + 6) * 256], v7 = xr[(8 * m + 7) * 256];
            q0 = __fadd_rn(q0, __fmul_rn(v0, v0));
            q1 = __fadd_rn(q1, __fmul_rn(v1, v1));
            q2 = __fadd_rn(q2, __fmul_rn(v2, v2));
            q3 = __fadd_rn(q3, __fmul_rn(v3, v3));
            q4 = __fadd_rn(q4, __fmul_rn(v4, v4));
            q5 = __fadd_rn(q5, __fmul_rn(v5, v5));
            q6 = __fadd_rn(q6, __fmul_rn(v6, v6));
            q7 = __fadd_rn(q7, __fmul_rn(v7, v7));
        }
        S[T1OFF + tid] = __fadd_rn(__fadd_rn(__fadd_rn(q0, q1), __fadd_rn(q2, q3)),
                                   __fadd_rn(__fadd_rn(q4, q5), __fadd_rn(q6, q7)));
    }
    __syncthreads();

    float t1r[8];
#pragma unroll
    for (int i = 0; i < 4; ++i) t1r[i] = S[T1OFF + row0 + i];
#pragma unroll
    for (int i = 4; i < 8; ++i) t1r[i] = S[T1OFF + 128 + row0 + (i - 4)];

    float best[8];
    int   bki[8];
#pragma unroll
    for (int i = 0; i < 8; ++i) { best[i] = INFINITY; bki[i] = 0; }

    // ---- k-loop: 4 sweeps of 8 k, NO barriers, e via base+imm-offset loads ----
#pragma unroll 1
    for (int s = 0; s < 4; ++s) {
        const int k0 = kt * 32 + s * 8;
        const float4* __restrict__ eb4 = (const float4*)(emb + (size_t)k0 * EDIM);

        float acc[8][8];
#pragma unroll
        for (int i = 0; i < 8; ++i)
#pragma unroll
            for (int j = 0; j < 8; ++j) acc[i][j] = 0.0f;

#pragma unroll 4
        for (int cc = 0; cc < 16; ++cc) {
            // 8 e-chunks: row j of this sweep, channels 4cc..4cc+3.
            // ONE base + constant offsets -> global_load_dwordx4 ... offset:N
            float4 e0 = eb4[0 * 16 + cc];
            float4 e1 = eb4[1 * 16 + cc];
            float4 e2 = eb4[2 * 16 + cc];
            float4 e3 = eb4[3 * 16 + cc];
            float4 e4 = eb4[4 * 16 + cc];
            float4 e5 = eb4[5 * 16 + cc];
            float4 e6 = eb4[6 * 16 + cc];
            float4 e7 = eb4[7 * 16 + cc];
#pragma unroll
            for (int q = 0; q < 4; ++q) {
                const int c = cc * 4 + q;
                // conflict-free: lanes -> consecutive float4s (byte 16*lane)
                const float4 xa = *(const float4*)&S[XOFF + c * 256 + row0];
                const float4 xb = *(const float4*)&S[XOFF + c * 256 + 128 + row0];
                const float eq0 = (q == 0) ? e0.x : (q == 1) ? e0.y : (q == 2) ? e0.z : e0.w;
                const float eq1 = (q == 0) ? e1.x : (q == 1) ? e1.y : (q == 2) ? e1.z : e1.w;
                const float eq2 = (q == 0) ? e2.x : (q == 1) ? e2.y : (q == 2) ? e2.z : e2.w;
                const float eq3 = (q == 0) ? e3.x : (q == 1) ? e3.y : (q == 2) ? e3.z : e3.w;
                const float eq4 = (q == 0) ? e4.x : (q == 1) ? e4.y : (q == 2) ? e4.z : e4.w;
                const float eq5 = (q == 0) ? e5.x : (q == 1) ? e5.y : (q == 2) ? e5.z : e5.w;
                const float eq6 = (q == 0) ? e6.x : (q == 1) ? e6.y : (q == 2) ? e6.z : e6.w;
                const float eq7 = (q == 0) ? e7.x : (q == 1) ? e7.y : (q == 2) ? e7.z : e7.w;
#define ROW(i, xv) \
                acc[i][0] = __fmaf_rn(xv, eq0, acc[i][0]); \
                acc[i][1] = __fmaf_rn(xv, eq1, acc[i][1]); \
                acc[i][2] = __fmaf_rn(xv, eq2, acc[i][2]); \
                acc[i][3] = __fmaf_rn(xv, eq3, acc[i][3]); \
                acc[i][4] = __fmaf_rn(xv, eq4, acc[i][4]); \
                acc[i][5] = __fmaf_rn(xv, eq5, acc[i][5]); \
                acc[i][6] = __fmaf_rn(xv, eq6, acc[i][6]); \
                acc[i][7] = __fmaf_rn(xv, eq7, acc[i][7]);
                ROW(0, xa.x) ROW(1, xa.y) ROW(2, xa.z) ROW(3, xa.w)
                ROW(4, xb.x) ROW(5, xb.y) ROW(6, xb.z) ROW(7, xb.w)
#undef ROW
            }
        }

        // finish: d = fl(fl(t1 + t2) - fl(2*p)); s,j ascending -> k ascending
#pragma unroll
        for (int j = 0; j < 8; ++j) {
            const int kg = k0 + j;
            const float t2k = S[T2OFF + kg];
#pragma unroll
            for (int i = 0; i < 8; ++i) {
                float d = __fsub_rn(__fadd_rn(t1r[i], t2k),
                                    __fmul_rn(2.0f, acc[i][j]));
                if (d < best[i]) { best[i] = d; bki[i] = kg; }
            }
        }
    }

    __syncthreads();   // all x reads done; CB/CK overlay the x region

    // ---- combine across the 16 k-threads ----
#pragma unroll
    for (int i = 0; i < 4; ++i) {
        S[CBOFF + kt * 256 + row0 + i] = best[i];
        ((int*)S)[CKOFF + kt * 256 + row0 + i] = bki[i];
    }
#pragma unroll
    for (int i = 4; i < 8; ++i) {
        S[CBOFF + kt * 256 + 128 + row0 + (i - 4)] = best[i];
        ((int*)S)[CKOFF + kt * 256 + 128 + row0 + (i - 4)] = bki[i];
    }
    __syncthreads();

    if (tid < 256) {
        const int row = tid;
        float B = INFINITY;
        int   K = 0;
        // lexicographic (d, k) min == numpy argmin lowest-index tie-break
#pragma unroll
        for (int q = 0; q < 16; ++q) {
            const float bq = S[CBOFF + q * 256 + row];
            const int   kq = ((int*)S)[CKOFF + q * 256 + row];
            if (bq < B || (bq == B && kq < K)) { B = bq; K = kq; }
        }

        // epilogue: x re-read from global (L2-hot; LDS x is overlaid)
        const float* eb = emb + (size_t)K * EDIM;
        float s = 0.0f;
#pragma unroll
        for (int c = 0; c < 64; ++c) {
            const float x = zb[(size_t)c * HW + row];   // coalesced lanes->row
            const float f = __fsub_rn(eb[c], x);
            out[((size_t)b * EDIM + c) * HW + hwb + row] = __fadd_rn(x, f);
            s = __fmaf_rn(f, f, s);
        }
        out[(size_t)NQ + 2 + bb * 256 + row] = (float)K;

#pragma unroll
        for (int off = 32; off > 0; off >>= 1) s += __shfl_down(s, off);
        if ((tid & 63) == 0) atomicAdd(ws_f, s);
    }
}

__global__ void vq_final(const float* __restrict__ ws_f, float* __restrict__ out) {
    float m = ws_f[0] * (1.0f / (float)NQ);   // 2^-23, exact scaling
    out[NQ + 0] = m;
    out[NQ + 1] = m;
}

extern "C" void kernel_launch(void* const* d_in, const int* in_sizes, int n_in,
                              void* d_out, int out_size, void* d_ws, size_t ws_size,
                              hipStream_t stream) {
    const float* z = (const float*)d_in[0];     // [32, 64, 64, 64] fp32
    const float* emb = (const float*)d_in[1];   // [512, 64] fp32
    float* out = (float*)d_out;
    float* ws_f = (float*)d_ws;

    hipLaunchKernelGGL(vq_prep, dim3(1), dim3(512), 0, stream, emb, ws_f);
    hipLaunchKernelGGL(vq_main, dim3(NROWS / 256), dim3(512), 0, stream, z, emb, out, ws_f);
    hipLaunchKernelGGL(vq_final, dim3(1), dim3(1), 0, stream, ws_f, out);
}

// Round 14
// 147.439 us; speedup vs baseline: 3.5635x; 2.1942x over previous
//
#include <hip/hip_runtime.h>
#include <math.h>

#define NUM_EMB 512
#define EDIM 64
#define BATCH 32
#define HW 4096
#define NROWS (BATCH * HW)        // 131072
#define NQ (NROWS * EDIM)         // 8388608

// LDS layout in floats (17152 floats = 68608 B -> 2 blocks/CU)
#define XOFF 0                    // x_t[c][r] : c*256 + r  (64 x 256)
#define T2OFF 16384               // t2[512]
#define T1OFF 16896               // t1[256]
#define CBOFF 0                   // combine best [kt][256]  (overlays x post-loop)
#define CKOFF 4096                // combine bestk [kt][256] (int, overlays x)
#define SFLOATS 17152

// numpy pairwise_sum for n=64 contiguous fp32 (tiny prep kernel only).
__device__ __forceinline__ float pairwise8_64(const float* v) {
    float r0 = v[0], r1 = v[1], r2 = v[2], r3 = v[3];
    float r4 = v[4], r5 = v[5], r6 = v[6], r7 = v[7];
#pragma unroll
    for (int i = 8; i < 64; i += 8) {
        r0 = __fadd_rn(r0, v[i + 0]);
        r1 = __fadd_rn(r1, v[i + 1]);
        r2 = __fadd_rn(r2, v[i + 2]);
        r3 = __fadd_rn(r3, v[i + 3]);
        r4 = __fadd_rn(r4, v[i + 4]);
        r5 = __fadd_rn(r5, v[i + 5]);
        r6 = __fadd_rn(r6, v[i + 6]);
        r7 = __fadd_rn(r7, v[i + 7]);
    }
    return __fadd_rn(__fadd_rn(__fadd_rn(r0, r1), __fadd_rn(r2, r3)),
                     __fadd_rn(__fadd_rn(r4, r5), __fadd_rn(r6, r7)));
}

// ws_f layout: [0] = loss sum accumulator, [8..8+511] = t2[k] = ||emb_k||^2
__global__ void vq_prep(const float* __restrict__ emb, float* __restrict__ ws_f) {
    int k = blockIdx.x * blockDim.x + threadIdx.x;
    if (k == 0) ws_f[0] = 0.0f;
    if (k < NUM_EMB) {
        const float* e = emb + k * EDIM;
        float sq[EDIM];
#pragma unroll
        for (int c = 0; c < EDIM; ++c) sq[c] = __fmul_rn(e[c], e[c]);
        ws_f[8 + k] = pairwise8_64(sq);
    }
}

// Round-14 = round-13 with the register-pressure bug fixed:
//  - cc-loop unroll 1 (round 13's unroll-4 hoisted 128 e-regs -> acc spilled
//    to scratch: VGPR 64, WRITE_SIZE 396MB, 21% VALU)
//  - launch_bounds (512,2): allocator headroom; occupancy is LDS-bound at
//    2 blocks/CU (68.6KB) -> 4 waves/SIMD either way.
// Hot loop: x from LDS (conflict-free b128, only LDS user), e from global via
// ONE base + compile-time offsets (offset <= 2032) on the in-order vmcnt path,
// L1-resident 8KB sweep working set. Per (row,k): ONE ascending-c FMA chain
// -> bit-exact (verified absmax 0.0 rounds 1-13).
__global__ __launch_bounds__(512, 2) void vq_main(const float* __restrict__ z,
                                                  const float* __restrict__ emb,
                                                  float* __restrict__ out,
                                                  float* __restrict__ ws_f) {
    __shared__ float S[SFLOATS];
    const int tid = threadIdx.x;
    const int rt  = tid & 31;       // row-thread
    const int kt  = tid >> 5;       // k-thread: 16, each owns k in [kt*32,kt*32+32)
    const int row0 = rt * 4;        // rows row0+i and 128+row0+i (conflict-free)
    const int bb  = blockIdx.x;
    const int b   = bb >> 4;        // batch (16 blocks per batch image)
    const int hwb = (bb & 15) << 8; // block's hw base (256 rows)

    const float* zb = z + (size_t)b * (EDIM * HW) + hwb;

    // ---- stage x_t[c][r] (transposed) + t2 ----
    {
        const int r = tid & 255, ch = tid >> 8;
#pragma unroll
        for (int j = 0; j < 32; ++j) {
            const int c = ch * 32 + j;
            S[XOFF + c * 256 + r] = zb[(size_t)c * HW + r];  // coalesced lanes->r
        }
    }
    S[T2OFF + tid] = ws_f[8 + tid];
    __syncthreads();

    // ---- t1 per row: numpy pairwise-8, ascending c, from x_t ----
    if (tid < 256) {
        const float* xr = &S[XOFF + tid];   // stride 256 per c
        float q0 = __fmul_rn(xr[0 * 256], xr[0 * 256]);
        float q1 = __fmul_rn(xr[1 * 256], xr[1 * 256]);
        float q2 = __fmul_rn(xr[2 * 256], xr[2 * 256]);
        float q3 = __fmul_rn(xr[3 * 256], xr[3 * 256]);
        float q4 = __fmul_rn(xr[4 * 256], xr[4 * 256]);
        float q5 = __fmul_rn(xr[5 * 256], xr[5 * 256]);
        float q6 = __fmul_rn(xr[6 * 256], xr[6 * 256]);
        float q7 = __fmul_rn(xr[7 * 256], xr[7 * 256]);
#pragma unroll
        for (int m = 1; m < 8; ++m) {
            float v0 = xr[(8 * m + 0) * 256], v1 = xr[(8 * m + 1) * 256];
            float v2 = xr[(8 * m + 2) * 256], v3 = xr[(8 * m + 3) * 256];
            float v4 = xr[(8 * m + 4) * 256], v5 = xr[(8 * m + 5) * 256];
            float v6 = xr[(8 * m + 6) * 256], v7 = xr[(8 * m + 7) * 256];
            q0 = __fadd_rn(q0, __fmul_rn(v0, v0));
            q1 = __fadd_rn(q1, __fmul_rn(v1, v1));
            q2 = __fadd_rn(q2, __fmul_rn(v2, v2));
            q3 = __fadd_rn(q3, __fmul_rn(v3, v3));
            q4 = __fadd_rn(q4, __fmul_rn(v4, v4));
            q5 = __fadd_rn(q5, __fmul_rn(v5, v5));
            q6 = __fadd_rn(q6, __fmul_rn(v6, v6));
            q7 = __fadd_rn(q7, __fmul_rn(v7, v7));
        }
        S[T1OFF + tid] = __fadd_rn(__fadd_rn(__fadd_rn(q0, q1), __fadd_rn(q2, q3)),
                                   __fadd_rn(__fadd_rn(q4, q5), __fadd_rn(q6, q7)));
    }
    __syncthreads();

    float t1r[8];
#pragma unroll
    for (int i = 0; i < 4; ++i) t1r[i] = S[T1OFF + row0 + i];
#pragma unroll
    for (int i = 4; i < 8; ++i) t1r[i] = S[T1OFF + 128 + row0 + (i - 4)];

    float best[8];
    int   bki[8];
#pragma unroll
    for (int i = 0; i < 8; ++i) { best[i] = INFINITY; bki[i] = 0; }

    // ---- k-loop: 4 sweeps of 8 k, NO barriers, e via base+imm-offset loads ----
#pragma unroll 1
    for (int s = 0; s < 4; ++s) {
        const int k0 = kt * 32 + s * 8;
        const float4* __restrict__ eb4 = (const float4*)(emb + (size_t)k0 * EDIM);

        float acc[8][8];
#pragma unroll
        for (int i = 0; i < 8; ++i)
#pragma unroll
            for (int j = 0; j < 8; ++j) acc[i][j] = 0.0f;

#pragma unroll 1
        for (int cc = 0; cc < 16; ++cc) {
            // 8 e-chunks: k-row j of this sweep, channels 4cc..4cc+3.
            // ONE base + constant offsets -> global_load_dwordx4 ... offset:N
            float4 e0 = eb4[0 * 16 + cc];
            float4 e1 = eb4[1 * 16 + cc];
            float4 e2 = eb4[2 * 16 + cc];
            float4 e3 = eb4[3 * 16 + cc];
            float4 e4 = eb4[4 * 16 + cc];
            float4 e5 = eb4[5 * 16 + cc];
            float4 e6 = eb4[6 * 16 + cc];
            float4 e7 = eb4[7 * 16 + cc];
#pragma unroll
            for (int q = 0; q < 4; ++q) {
                const int c = cc * 4 + q;
                // conflict-free: lanes -> consecutive float4s (byte 16*lane)
                const float4 xa = *(const float4*)&S[XOFF + c * 256 + row0];
                const float4 xb = *(const float4*)&S[XOFF + c * 256 + 128 + row0];
                const float eq0 = (q == 0) ? e0.x : (q == 1) ? e0.y : (q == 2) ? e0.z : e0.w;
                const float eq1 = (q == 0) ? e1.x : (q == 1) ? e1.y : (q == 2) ? e1.z : e1.w;
                const float eq2 = (q == 0) ? e2.x : (q == 1) ? e2.y : (q == 2) ? e2.z : e2.w;
                const float eq3 = (q == 0) ? e3.x : (q == 1) ? e3.y : (q == 2) ? e3.z : e3.w;
                const float eq4 = (q == 0) ? e4.x : (q == 1) ? e4.y : (q == 2) ? e4.z : e4.w;
                const float eq5 = (q == 0) ? e5.x : (q == 1) ? e5.y : (q == 2) ? e5.z : e5.w;
                const float eq6 = (q == 0) ? e6.x : (q == 1) ? e6.y : (q == 2) ? e6.z : e6.w;
                const float eq7 = (q == 0) ? e7.x : (q == 1) ? e7.y : (q == 2) ? e7.z : e7.w;
#define ROW(i, xv) \
                acc[i][0] = __fmaf_rn(xv, eq0, acc[i][0]); \
                acc[i][1] = __fmaf_rn(xv, eq1, acc[i][1]); \
                acc[i][2] = __fmaf_rn(xv, eq2, acc[i][2]); \
                acc[i][3] = __fmaf_rn(xv, eq3, acc[i][3]); \
                acc[i][4] = __fmaf_rn(xv, eq4, acc[i][4]); \
                acc[i][5] = __fmaf_rn(xv, eq5, acc[i][5]); \
                acc[i][6] = __fmaf_rn(xv, eq6, acc[i][6]); \
                acc[i][7] = __fmaf_rn(xv, eq7, acc[i][7]);
                ROW(0, xa.x) ROW(1, xa.y) ROW(2, xa.z) ROW(3, xa.w)
                ROW(4, xb.x) ROW(5, xb.y) ROW(6, xb.z) ROW(7, xb.w)
#undef ROW
            }
        }

        // finish: d = fl(fl(t1 + t2) - fl(2*p)); s,j ascending -> k ascending
#pragma unroll
        for (int j = 0; j < 8; ++j) {
            const int kg = k0 + j;
            const float t2k = S[T2OFF + kg];
#pragma unroll
            for (int i = 0; i < 8; ++i) {
                float d = __fsub_rn(__fadd_rn(t1r[i], t2k),
                                    __fmul_rn(2.0f, acc[i][j]));
                if (d < best[i]) { best[i] = d; bki[i] = kg; }
            }
        }
    }

    __syncthreads();   // all x reads done; CB/CK overlay the x region

    // ---- combine across the 16 k-threads ----
#pragma unroll
    for (int i = 0; i < 4; ++i) {
        S[CBOFF + kt * 256 + row0 + i] = best[i];
        ((int*)S)[CKOFF + kt * 256 + row0 + i] = bki[i];
    }
#pragma unroll
    for (int i = 4; i < 8; ++i) {
        S[CBOFF + kt * 256 + 128 + row0 + (i - 4)] = best[i];
        ((int*)S)[CKOFF + kt * 256 + 128 + row0 + (i - 4)] = bki[i];
    }
    __syncthreads();

    if (tid < 256) {
        const int row = tid;
        float B = INFINITY;
        int   K = 0;
        // lexicographic (d, k) min == numpy argmin lowest-index tie-break
#pragma unroll
        for (int q = 0; q < 16; ++q) {
            const float bq = S[CBOFF + q * 256 + row];
            const int   kq = ((int*)S)[CKOFF + q * 256 + row];
            if (bq < B || (bq == B && kq < K)) { B = bq; K = kq; }
        }

        // epilogue: x re-read from global (L2-hot; LDS x is overlaid)
        const float* eb = emb + (size_t)K * EDIM;
        float s = 0.0f;
#pragma unroll
        for (int c = 0; c < 64; ++c) {
            const float x = zb[(size_t)c * HW + row];   // coalesced lanes->row
            const float f = __fsub_rn(eb[c], x);
            out[((size_t)b * EDIM + c) * HW + hwb + row] = __fadd_rn(x, f);
            s = __fmaf_rn(f, f, s);
        }
        out[(size_t)NQ + 2 + bb * 256 + row] = (float)K;

#pragma unroll
        for (int off = 32; off > 0; off >>= 1) s += __shfl_down(s, off);
        if ((tid & 63) == 0) atomicAdd(ws_f, s);
    }
}

__global__ void vq_final(const float* __restrict__ ws_f, float* __restrict__ out) {
    float m = ws_f[0] * (1.0f / (float)NQ);   // 2^-23, exact scaling
    out[NQ + 0] = m;
    out[NQ + 1] = m;
}

extern "C" void kernel_launch(void* const* d_in, const int* in_sizes, int n_in,
                              void* d_out, int out_size, void* d_ws, size_t ws_size,
                              hipStream_t stream) {
    const float* z = (const float*)d_in[0];     // [32, 64, 64, 64] fp32
    const float* emb = (const float*)d_in[1];   // [512, 64] fp32
    float* out = (float*)d_out;
    float* ws_f = (float*)d_ws;

    hipLaunchKernelGGL(vq_prep, dim3(1), dim3(512), 0, stream, emb, ws_f);
    hipLaunchKernelGGL(vq_main, dim3(NROWS / 256), dim3(512), 0, stream, z, emb, out, ws_f);
    hipLaunchKernelGGL(vq_final, dim3(1), dim3(1), 0, stream, ws_f, out);
}